// Round 6
// baseline (465.942 us; speedup 1.0000x reference)
//
#include <hip/hip_runtime.h>

// ---------------------------------------------------------------------------
// RGCN link predictor. Atomic-free CSR build + CSR-pull + split-bf16 MFMA GEMM.
//   rgcn_conv(x) = x@root + b + sum_r segsum_dst( H_r[src] ) / max(cnt_r[dst],1)
//   CSR build: MSD 2-level bucket sort by dst, LDS-local returning atomics only.
//   GEMM: fp32 via bf16 split (Ah*Bh + Al*Bh + Ah*Bl). A-fragments are loaded
//   DIRECTLY global->register (16x16x32 A-frag = 8 contiguous row elements),
//   split in-register: no LDS, no barriers, no bank conflicts.
//   B pre-packed to fragment order in global (128 KB, L1-resident).
// ---------------------------------------------------------------------------

typedef short bf16x8 __attribute__((ext_vector_type(8)));
typedef float f32x4 __attribute__((ext_vector_type(4)));

__device__ __forceinline__ unsigned short f2bf(float f) {
  union { float f; unsigned u; } x; x.f = f;
  unsigned r = x.u + 0x7FFF + ((x.u >> 16) & 1);  // RNE
  return (unsigned short)(r >> 16);
}
__device__ __forceinline__ float bf2f(unsigned short h) {
  union { unsigned u; float f; } x; x.u = ((unsigned)h) << 16;
  return x.f;
}

// ---- level-1 partition: histogram of dst>>9 per block tile ----
__global__ __launch_bounds__(256) void part_hist_kernel(
    const int* __restrict__ ei, int* __restrict__ hist,
    int E, int tile, int NBUCK) {
  __shared__ int lh[256];
  int tid = threadIdx.x;
  lh[tid] = 0;
  __syncthreads();
  int e0 = blockIdx.x * tile;
  int e1 = min(E, e0 + tile);
  for (int e = e0 + tid; e < e1; e += 256) {
    int d = ei[E + e];
    atomicAdd(&lh[d >> 9], 1);
  }
  __syncthreads();
  if (tid < NBUCK) hist[tid * 256 + blockIdx.x] = lh[tid];
}

// scan hist rows (bucket-major) + bucket bases; rewrite hist to global cursors
__global__ __launch_bounds__(256) void part_scan_kernel(
    int* __restrict__ hist, int* __restrict__ bstart, int NBUCK) {
  __shared__ int sA[256], sB[256];
  int t = threadIdx.x;
  int tot = 0;
  if (t < NBUCK) {
    int* row = hist + t * 256;
    for (int i = 0; i < 256; i++) { int v = row[i]; row[i] = tot; tot += v; }
  }
  sA[t] = tot;
  __syncthreads();
  int* src = sA; int* dst = sB;
  for (int off = 1; off < 256; off <<= 1) {
    int v = src[t];
    if (t >= off) v += src[t - off];
    dst[t] = v;
    __syncthreads();
    int* tmp = src; src = dst; dst = tmp;
  }
  int base = src[t] - tot;  // exclusive
  if (t < NBUCK) {
    bstart[t] = base;
    int* row = hist + t * 256;
    for (int i = 0; i < 256; i++) row[i] += base;
    if (t == NBUCK - 1) bstart[NBUCK] = base + tot;
  }
}

// scatter edges into coarse buckets (LDS cursors, plain global stores)
__global__ __launch_bounds__(256) void part_scatter_kernel(
    const int* __restrict__ ei, const int* __restrict__ et,
    const int* __restrict__ hist, uint2* __restrict__ rec,
    int E, int tile, int NBUCK) {
  __shared__ int ctr[256];
  int tid = threadIdx.x;
  ctr[tid] = (tid < NBUCK) ? hist[tid * 256 + blockIdx.x] : 0;
  __syncthreads();
  int e0 = blockIdx.x * tile;
  int e1 = min(E, e0 + tile);
  for (int e = e0 + tid; e < e1; e += 256) {
    int s = ei[e];
    int d = ei[E + e];
    int t = et[e];
    int p = atomicAdd(&ctr[d >> 9], 1);
    rec[p] = make_uint2((unsigned)(s | (t << 20)), (unsigned)d);
  }
}

// ---- level-2: one block per bucket (dst window of 512). Produces per-(rel,dst)
// inv, deg, startp and the final dst-grouped eSrcT — LDS atomics only.
__global__ __launch_bounds__(256) void bucket_build_kernel(
    const uint2* __restrict__ rec, const int* __restrict__ bstart,
    float* __restrict__ inv, int* __restrict__ deg, int* __restrict__ startp,
    int* __restrict__ eSrcT, int N) {
  __shared__ int c3[1536];
  __shared__ int sA[512], sB[512];
  __shared__ int cur[512];
  int tid = threadIdx.x;
  int dstBase = blockIdx.x << 9;
  int bs = bstart[blockIdx.x], be = bstart[blockIdx.x + 1];
  for (int i = tid; i < 1536; i += 256) c3[i] = 0;
  __syncthreads();
  for (int i = bs + tid; i < be; i += 256) {
    uint2 r = rec[i];
    atomicAdd(&c3[(r.x >> 20) * 512 + (r.y & 511)], 1);
  }
  __syncthreads();
  for (int i = tid; i < 512; i += 256) {
    int d = dstBase + i;
    int c0 = c3[i], c1 = c3[512 + i], c2 = c3[1024 + i];
    int dg = c0 + c1 + c2;
    sA[i] = dg;
    if (d < N) {
      deg[d] = dg;
      inv[d]         = 1.0f / (float)max(c0, 1);
      inv[N + d]     = 1.0f / (float)max(c1, 1);
      inv[2 * N + d] = 1.0f / (float)max(c2, 1);
    }
  }
  __syncthreads();
  int* src = sA; int* dst = sB;
  for (int off = 1; off < 512; off <<= 1) {
    for (int i = tid; i < 512; i += 256) {
      int v = src[i];
      if (i >= off) v += src[i - off];
      dst[i] = v;
    }
    __syncthreads();
    int* tmp = src; src = dst; dst = tmp;
  }
  for (int i = tid; i < 512; i += 256) {
    int excl = (i > 0) ? src[i - 1] : 0;
    cur[i] = bs + excl;
    int d = dstBase + i;
    if (d < N) startp[d] = bs + excl;
  }
  __syncthreads();
  for (int i = bs + tid; i < be; i += 256) {
    uint2 r = rec[i];
    int p = atomicAdd(&cur[r.y & 511], 1);
    eSrcT[p] = (int)r.x;
  }
}

// pack weights (3 relation slabs + root) into MFMA B-fragment order, split hi/lo.
__global__ __launch_bounds__(256) void packw_kernel(
    const float* __restrict__ W, const float* __restrict__ root,
    ushort* __restrict__ Bh, ushort* __restrict__ Bl, int K, int TN) {
  int e = blockIdx.x * 256 + threadIdx.x;
  if (e >= 4 * K * TN) return;
  int slab = e / (K * TN), r = e % (K * TN);
  int k = r / TN, n = r % TN;
  float v = (slab < 3) ? W[(size_t)slab * K * TN + k * TN + n] : root[(size_t)k * TN + n];
  int kc = k >> 5, quad = (k >> 3) & 3, j = k & 7, nt = n >> 4, nn = n & 15;
  int NTt = TN / 16;
  int didx = slab * K * TN + ((kc * NTt + nt) * 64 + quad * 16 + nn) * 8 + j;
  unsigned short h = f2bf(v);
  Bh[didx] = h;
  Bl[didx] = f2bf(v - bf2f(h));
}

// Split-bf16 MFMA GEMM, LDS-free. One wave per 32 rows (2 m-tiles of 16).
// A-fragment (m=lane&15, k=quad*8+j) = 8 contiguous row-major elements ->
// direct global->register float4 loads, hi/lo split in-register.
// slabs 0..2 -> H[slab] = A@W[slab]; slab 3 -> z = A@root + bias.
template <int K, int TN>
__global__ __launch_bounds__(256, 3) void mfma_gemm_kernel(
    const float* __restrict__ A, const ushort* __restrict__ Bh,
    const ushort* __restrict__ Bl, const float* __restrict__ bias,
    float* __restrict__ H, float* __restrict__ z, int n) {
  constexpr int KC = K / 32;   // 32-k chunks
  constexpr int NTt = TN / 16; // col tiles
  const int gwave = (blockIdx.x * 256 + threadIdx.x) >> 6;
  const int lane = threadIdx.x & 63;
  const int quad = lane >> 4, nn = lane & 15;
  const int rowBase = gwave * 32;
  if (rowBase >= n) return;

  // ---- load A fragments, split hi/lo in-register ----
  bf16x8 ah[2][KC], al[2][KC];
#pragma unroll
  for (int mt = 0; mt < 2; mt++) {
    int row = rowBase + mt * 16 + nn;
    if (row >= n) row = n - 1;  // safe clamp; those results are never stored
    const float* ap = &A[(size_t)row * K + quad * 8];
#pragma unroll
    for (int kc = 0; kc < KC; kc++) {
      float4 f0 = *(const float4*)(ap + kc * 32);
      float4 f1 = *(const float4*)(ap + kc * 32 + 4);
      float f[8] = {f0.x, f0.y, f0.z, f0.w, f1.x, f1.y, f1.z, f1.w};
      bf16x8 vh, vl;
#pragma unroll
      for (int j = 0; j < 8; j++) {
        unsigned short h = f2bf(f[j]);
        vh[j] = (short)h;
        vl[j] = (short)f2bf(f[j] - bf2f(h));
      }
      ah[mt][kc] = vh;
      al[mt][kc] = vl;
    }
  }

#pragma unroll 1
  for (int slab = 0; slab < 4; slab++) {
    f32x4 acc[2][NTt];
#pragma unroll
    for (int i = 0; i < 2; i++)
#pragma unroll
      for (int j = 0; j < NTt; j++) acc[i][j] = (f32x4){0.f, 0.f, 0.f, 0.f};

    // one split-product pass: acc += Af @ Bfrag
    auto do_pass = [&](const bf16x8 (&Af)[2][KC], const ushort* Bs) {
#pragma unroll
      for (int kc = 0; kc < KC; kc++) {
#pragma unroll
        for (int nt = 0; nt < NTt; nt++) {
          bf16x8 b = *(const bf16x8*)&Bs[((kc * NTt + nt) * 64 + lane) * 8];
          acc[0][nt] = __builtin_amdgcn_mfma_f32_16x16x32_bf16(Af[0][kc], b, acc[0][nt], 0, 0, 0);
          acc[1][nt] = __builtin_amdgcn_mfma_f32_16x16x32_bf16(Af[1][kc], b, acc[1][nt], 0, 0, 0);
        }
      }
    };
    const ushort* BhS = Bh + (size_t)slab * K * TN;
    const ushort* BlS = Bl + (size_t)slab * K * TN;
    do_pass(ah, BhS);  // Ah*Bh
    do_pass(al, BhS);  // Al*Bh
    do_pass(ah, BlS);  // Ah*Bl

    // epilogue: D row = quad*4+reg, col = lane&15 (m89-verified)
#pragma unroll
    for (int mt = 0; mt < 2; mt++) {
      int grow0 = rowBase + mt * 16 + quad * 4;
#pragma unroll
      for (int nt = 0; nt < NTt; nt++) {
        int col = nt * 16 + nn;
#pragma unroll
        for (int rg = 0; rg < 4; rg++) {
          int grow = grow0 + rg;
          if (grow < n) {
            float v = acc[mt][nt][rg];
            if (slab == 3) z[(size_t)grow * TN + col] = v + bias[col];
            else H[((size_t)slab * n + grow) * TN + col] = v;
          }
        }
      }
    }
  }
}

// ---- pull, C=64: one wave per node; 16 lanes x float4 per edge, 4 edges/iter.
__global__ __launch_bounds__(256) void pull64_kernel(
    const float4* __restrict__ H4, const int* __restrict__ eSrcT,
    const int* __restrict__ startp, const int* __restrict__ deg,
    const float* __restrict__ inv, float* __restrict__ z, int N) {
  int w = (blockIdx.x * 256 + threadIdx.x) >> 6;
  if (w >= N) return;
  int lane = threadIdx.x & 63;
  int g = lane >> 4;
  int q = lane & 15;
  int st = startp[w];
  int dg = deg[w];
  float sc0 = inv[w], sc1 = inv[N + w], sc2 = inv[2 * N + w];
  float4 acc = make_float4(0.f, 0.f, 0.f, 0.f);
  for (int i = g; i < dg; i += 4) {
    int p = eSrcT[st + i];
    int s = p & 0xFFFFF;
    int t = p >> 20;
    float sc = (t == 0) ? sc0 : ((t == 1) ? sc1 : sc2);
    float4 v = H4[((size_t)t * N + s) * 16 + q];
    acc.x += v.x * sc; acc.y += v.y * sc; acc.z += v.z * sc; acc.w += v.w * sc;
  }
#pragma unroll
  for (int m = 16; m <= 32; m <<= 1) {
    acc.x += __shfl_xor(acc.x, m);
    acc.y += __shfl_xor(acc.y, m);
    acc.z += __shfl_xor(acc.z, m);
    acc.w += __shfl_xor(acc.w, m);
  }
  if (g == 0) {
    float4* zp = (float4*)z + (size_t)w * 16 + q;
    float4 zv = *zp;
    zv.x = fmaxf(zv.x + acc.x, 0.f);
    zv.y = fmaxf(zv.y + acc.y, 0.f);
    zv.z = fmaxf(zv.z + acc.z, 0.f);
    zv.w = fmaxf(zv.w + acc.w, 0.f);
    *zp = zv;
  }
}

// ---- pull, C=32: 8 lanes x float4 per edge, 8 edges/iter. No ReLU.
__global__ __launch_bounds__(256) void pull32_kernel(
    const float4* __restrict__ H4, const int* __restrict__ eSrcT,
    const int* __restrict__ startp, const int* __restrict__ deg,
    const float* __restrict__ inv, float* __restrict__ z, int N) {
  int w = (blockIdx.x * 256 + threadIdx.x) >> 6;
  if (w >= N) return;
  int lane = threadIdx.x & 63;
  int g = lane >> 3;
  int q = lane & 7;
  int st = startp[w];
  int dg = deg[w];
  float sc0 = inv[w], sc1 = inv[N + w], sc2 = inv[2 * N + w];
  float4 acc = make_float4(0.f, 0.f, 0.f, 0.f);
  for (int i = g; i < dg; i += 8) {
    int p = eSrcT[st + i];
    int s = p & 0xFFFFF;
    int t = p >> 20;
    float sc = (t == 0) ? sc0 : ((t == 1) ? sc1 : sc2);
    float4 v = H4[((size_t)t * N + s) * 8 + q];
    acc.x += v.x * sc; acc.y += v.y * sc; acc.z += v.z * sc; acc.w += v.w * sc;
  }
#pragma unroll
  for (int m = 8; m <= 32; m <<= 1) {
    acc.x += __shfl_xor(acc.x, m);
    acc.y += __shfl_xor(acc.y, m);
    acc.z += __shfl_xor(acc.z, m);
    acc.w += __shfl_xor(acc.w, m);
  }
  if (g == 0) {
    float4* zp = (float4*)z + (size_t)w * 8 + q;
    float4 zv = *zp;
    zv.x += acc.x; zv.y += acc.y; zv.z += acc.z; zv.w += acc.w;
    *zp = zv;
  }
}

// Decoder: one thread per pred edge. Wd1 broadcast from LDS.
__global__ __launch_bounds__(256) void decoder_kernel(
    const float* __restrict__ z, const int* __restrict__ pe,
    const float* __restrict__ Wd1, const float* __restrict__ bd1,
    const float* __restrict__ Wd2, const float* __restrict__ bd2,
    float* __restrict__ out, int P) {
  __shared__ float W[64 * 64];
  __shared__ float w2[64], b1s[64];
  int tid = threadIdx.x;
  for (int i = tid * 4; i < 4096; i += 1024) *(float4*)&W[i] = *(const float4*)&Wd1[i];
  if (tid < 64) {
    w2[tid] = Wd2[tid];
    b1s[tid] = bd1[tid];
  }
  __syncthreads();
  int p = blockIdx.x * 256 + tid;
  if (p >= P) return;
  int s = pe[p];
  int d = pe[P + p];
  float zs[32], zd[32];
  const float4* ps4 = (const float4*)&z[(size_t)s * 32];
  const float4* pd4 = (const float4*)&z[(size_t)d * 32];
#pragma unroll
  for (int i = 0; i < 8; i++) {
    float4 a = ps4[i];
    zs[4 * i] = a.x; zs[4 * i + 1] = a.y; zs[4 * i + 2] = a.z; zs[4 * i + 3] = a.w;
    float4 b = pd4[i];
    zd[4 * i] = b.x; zd[4 * i + 1] = b.y; zd[4 * i + 2] = b.z; zd[4 * i + 3] = b.w;
  }
  float acc = bd2[0];
#pragma unroll 4
  for (int j = 0; j < 64; j++) {
    float h = b1s[j];
#pragma unroll
    for (int i = 0; i < 32; i++) h += zs[i] * W[i * 64 + j];
#pragma unroll
    for (int i = 0; i < 32; i++) h += zd[i] * W[(32 + i) * 64 + j];
    h = fmaxf(h, 0.0f);
    acc += h * w2[j];
  }
  out[p] = acc;
}

extern "C" void kernel_launch(void* const* d_in, const int* in_sizes, int n_in,
                              void* d_out, int out_size, void* d_ws, size_t ws_size,
                              hipStream_t stream) {
  const float* x     = (const float*)d_in[0];
  const int*   ei    = (const int*)d_in[1];
  const int*   et    = (const int*)d_in[2];
  const int*   pe    = (const int*)d_in[3];
  const float* W1    = (const float*)d_in[4];
  const float* root1 = (const float*)d_in[5];
  const float* b1    = (const float*)d_in[6];
  const float* W2    = (const float*)d_in[7];
  const float* root2 = (const float*)d_in[8];
  const float* b2    = (const float*)d_in[9];
  const float* Wd1   = (const float*)d_in[10];
  const float* bd1   = (const float*)d_in[11];
  const float* Wd2   = (const float*)d_in[12];
  const float* bd2   = (const float*)d_in[13];
  float* out = (float*)d_out;

  const int N = in_sizes[0] / 128;  // 100000
  const int E = in_sizes[2];        // 1600000
  const int P = in_sizes[3] / 2;    // 200000

  const int NBUCK = (N + 511) >> 9;         // coarse buckets (dst>>9), <=256
  const int tile  = (E + 255) / 256;        // edges per partition block

  // Workspace layout (float units; all offsets 16B-aligned for even N):
  //   inv:0..4N  z1:4N..68N  z2:68N..100N  H:100N..292N  Bpack:292N..293N
  //   ints from 293N: deg N | startp N | bstart 1K | hist NBUCK*256 | rec 2E | eSrcT E
  float* ws  = (float*)d_ws;
  float* inv = ws;
  float* z1  = ws + (size_t)4 * N;
  float* z2  = ws + (size_t)68 * N;
  float* H   = ws + (size_t)100 * N;
  ushort* Bh1 = (ushort*)(ws + (size_t)292 * N);  // 4*128*64
  ushort* Bl1 = Bh1 + 32768;
  ushort* Bh2 = Bl1 + 32768;                      // 4*64*32
  ushort* Bl2 = Bh2 + 8192;
  int* ib     = (int*)(ws + (size_t)293 * N);
  int* deg    = ib;
  int* startp = ib + N;
  int* bstart = ib + 2 * (size_t)N;               // NBUCK+1 (pad to 1024)
  int* hist   = ib + 2 * (size_t)N + 1024;        // NBUCK*256
  size_t roff = 2 * (size_t)N + 1024 + (size_t)NBUCK * 256;
  roff = (roff + 3) & ~(size_t)3;                 // 16B align for uint2
  uint2* rec  = (uint2*)(ib + roff);              // E records
  int* eSrcT  = ib + roff + 2 * (size_t)E;        // E

  // --- CSR build: 2-level bucket sort, LDS atomics only ---
  part_hist_kernel<<<256, 256, 0, stream>>>(ei, hist, E, tile, NBUCK);
  part_scan_kernel<<<1, 256, 0, stream>>>(hist, bstart, NBUCK);
  part_scatter_kernel<<<256, 256, 0, stream>>>(ei, et, hist, rec, E, tile, NBUCK);
  bucket_build_kernel<<<NBUCK, 256, 0, stream>>>(rec, bstart, inv, deg, startp, eSrcT, N);

  // --- weight packing (tiny) ---
  packw_kernel<<<(4 * 128 * 64 + 255) / 256, 256, 0, stream>>>(W1, root1, Bh1, Bl1, 128, 64);
  packw_kernel<<<(4 * 64 * 32 + 255) / 256, 256, 0, stream>>>(W2, root2, Bh2, Bl2, 64, 32);

  const int gb = (N + 127) / 128;  // 1 block = 4 waves = 128 rows
  const int pullBlocks = (N * 64 + 255) / 256;

  // --- layer 1: K=128 -> 64 ---
  mfma_gemm_kernel<128, 64><<<gb, 256, 0, stream>>>(x, Bh1, Bl1, b1, H, z1, N);
  pull64_kernel<<<pullBlocks, 256, 0, stream>>>((const float4*)H, eSrcT, startp, deg, inv, z1, N);

  // --- layer 2: K=64 -> 32 ---
  mfma_gemm_kernel<64, 32><<<gb, 256, 0, stream>>>(z1, Bh2, Bl2, b2, H, z2, N);
  pull32_kernel<<<pullBlocks, 256, 0, stream>>>((const float4*)H, eSrcT, startp, deg, inv, z2, N);

  // --- decoder ---
  decoder_kernel<<<(P + 255) / 256, 256, 0, stream>>>(z2, pe, Wd1, bd1, Wd2, bd2, out, P);
}

// Round 7
// 419.044 us; speedup vs baseline: 1.1119x; 1.1119x over previous
//
#include <hip/hip_runtime.h>

// ---------------------------------------------------------------------------
// RGCN link predictor. Atomic-free CSR build + CSR-pull + split-bf16 MFMA GEMM.
//   rgcn_conv(x) = x@root + b + sum_r segsum_dst( H_r[src] ) / max(cnt_r[dst],1)
//   CSR build: MSD 2-level bucket sort by dst, LDS-local returning atomics only.
//   GEMM: fp32 via bf16 split (Ah*Bh + Al*Bh + Ah*Bl). One 16-row m-tile per
//   wave (no spills); A-frags direct global->register (8 contiguous row elems);
//   B staged per-slab into LDS (ds_read_b128, conflict-free, Bh shared by 2
//   passes). B pre-packed to fragment order in global.
// ---------------------------------------------------------------------------

typedef short bf16x8 __attribute__((ext_vector_type(8)));
typedef float f32x4 __attribute__((ext_vector_type(4)));

__device__ __forceinline__ unsigned short f2bf(float f) {
  union { float f; unsigned u; } x; x.f = f;
  unsigned r = x.u + 0x7FFF + ((x.u >> 16) & 1);  // RNE
  return (unsigned short)(r >> 16);
}
__device__ __forceinline__ float bf2f(unsigned short h) {
  union { unsigned u; float f; } x; x.u = ((unsigned)h) << 16;
  return x.f;
}

// ---- level-1 partition: histogram of dst>>9 per block tile ----
__global__ __launch_bounds__(256) void part_hist_kernel(
    const int* __restrict__ ei, int* __restrict__ hist,
    int E, int tile, int NBUCK) {
  __shared__ int lh[256];
  int tid = threadIdx.x;
  lh[tid] = 0;
  __syncthreads();
  int e0 = blockIdx.x * tile;
  int e1 = min(E, e0 + tile);
  for (int e = e0 + tid; e < e1; e += 256) {
    int d = ei[E + e];
    atomicAdd(&lh[d >> 9], 1);
  }
  __syncthreads();
  if (tid < NBUCK) hist[tid * 256 + blockIdx.x] = lh[tid];
}

// scan hist rows (bucket-major) + bucket bases; rewrite hist to global cursors
__global__ __launch_bounds__(256) void part_scan_kernel(
    int* __restrict__ hist, int* __restrict__ bstart, int NBUCK) {
  __shared__ int sA[256], sB[256];
  int t = threadIdx.x;
  int tot = 0;
  if (t < NBUCK) {
    int* row = hist + t * 256;
    for (int i = 0; i < 256; i++) { int v = row[i]; row[i] = tot; tot += v; }
  }
  sA[t] = tot;
  __syncthreads();
  int* src = sA; int* dst = sB;
  for (int off = 1; off < 256; off <<= 1) {
    int v = src[t];
    if (t >= off) v += src[t - off];
    dst[t] = v;
    __syncthreads();
    int* tmp = src; src = dst; dst = tmp;
  }
  int base = src[t] - tot;  // exclusive
  if (t < NBUCK) {
    bstart[t] = base;
    int* row = hist + t * 256;
    for (int i = 0; i < 256; i++) row[i] += base;
    if (t == NBUCK - 1) bstart[NBUCK] = base + tot;
  }
}

// scatter edges into coarse buckets (LDS cursors, plain global stores)
__global__ __launch_bounds__(256) void part_scatter_kernel(
    const int* __restrict__ ei, const int* __restrict__ et,
    const int* __restrict__ hist, uint2* __restrict__ rec,
    int E, int tile, int NBUCK) {
  __shared__ int ctr[256];
  int tid = threadIdx.x;
  ctr[tid] = (tid < NBUCK) ? hist[tid * 256 + blockIdx.x] : 0;
  __syncthreads();
  int e0 = blockIdx.x * tile;
  int e1 = min(E, e0 + tile);
  for (int e = e0 + tid; e < e1; e += 256) {
    int s = ei[e];
    int d = ei[E + e];
    int t = et[e];
    int p = atomicAdd(&ctr[d >> 9], 1);
    rec[p] = make_uint2((unsigned)(s | (t << 20)), (unsigned)d);
  }
}

// ---- level-2: one block per bucket (dst window of 512). Produces per-(rel,dst)
// inv, deg, startp and the final dst-grouped eSrcT — LDS atomics only.
__global__ __launch_bounds__(256) void bucket_build_kernel(
    const uint2* __restrict__ rec, const int* __restrict__ bstart,
    float* __restrict__ inv, int* __restrict__ deg, int* __restrict__ startp,
    int* __restrict__ eSrcT, int N) {
  __shared__ int c3[1536];
  __shared__ int sA[512], sB[512];
  __shared__ int cur[512];
  int tid = threadIdx.x;
  int dstBase = blockIdx.x << 9;
  int bs = bstart[blockIdx.x], be = bstart[blockIdx.x + 1];
  for (int i = tid; i < 1536; i += 256) c3[i] = 0;
  __syncthreads();
  for (int i = bs + tid; i < be; i += 256) {
    uint2 r = rec[i];
    atomicAdd(&c3[(r.x >> 20) * 512 + (r.y & 511)], 1);
  }
  __syncthreads();
  for (int i = tid; i < 512; i += 256) {
    int d = dstBase + i;
    int c0 = c3[i], c1 = c3[512 + i], c2 = c3[1024 + i];
    int dg = c0 + c1 + c2;
    sA[i] = dg;
    if (d < N) {
      deg[d] = dg;
      inv[d]         = 1.0f / (float)max(c0, 1);
      inv[N + d]     = 1.0f / (float)max(c1, 1);
      inv[2 * N + d] = 1.0f / (float)max(c2, 1);
    }
  }
  __syncthreads();
  int* src = sA; int* dst = sB;
  for (int off = 1; off < 512; off <<= 1) {
    for (int i = tid; i < 512; i += 256) {
      int v = src[i];
      if (i >= off) v += src[i - off];
      dst[i] = v;
    }
    __syncthreads();
    int* tmp = src; src = dst; dst = tmp;
  }
  for (int i = tid; i < 512; i += 256) {
    int excl = (i > 0) ? src[i - 1] : 0;
    cur[i] = bs + excl;
    int d = dstBase + i;
    if (d < N) startp[d] = bs + excl;
  }
  __syncthreads();
  for (int i = bs + tid; i < be; i += 256) {
    uint2 r = rec[i];
    int p = atomicAdd(&cur[r.y & 511], 1);
    eSrcT[p] = (int)r.x;
  }
}

// pack weights (3 relation slabs + root) into MFMA B-fragment order, split hi/lo.
__global__ __launch_bounds__(256) void packw_kernel(
    const float* __restrict__ W, const float* __restrict__ root,
    ushort* __restrict__ Bh, ushort* __restrict__ Bl, int K, int TN) {
  int e = blockIdx.x * 256 + threadIdx.x;
  if (e >= 4 * K * TN) return;
  int slab = e / (K * TN), r = e % (K * TN);
  int k = r / TN, n = r % TN;
  float v = (slab < 3) ? W[(size_t)slab * K * TN + k * TN + n] : root[(size_t)k * TN + n];
  int kc = k >> 5, quad = (k >> 3) & 3, j = k & 7, nt = n >> 4, nn = n & 15;
  int NTt = TN / 16;
  int didx = slab * K * TN + ((kc * NTt + nt) * 64 + quad * 16 + nn) * 8 + j;
  unsigned short h = f2bf(v);
  Bh[didx] = h;
  Bl[didx] = f2bf(v - bf2f(h));
}

// Split-bf16 MFMA GEMM. Block = 4 waves x 16 rows = 64 rows.
// A-frag (m=lane&15, k=quad*8+j) = 8 contiguous row-major elems -> direct
// global->register, hi/lo split in-register (~70 VGPRs, no spill).
// B (hi+lo) staged per-slab into LDS; Bh frag read once, feeds Ah+Al MFMAs.
// slabs 0..2 -> H[slab] = A@W[slab]; slab 3 -> z = A@root + bias.
template <int K, int TN>
__global__ __launch_bounds__(256, 4) void mfma_gemm_kernel(
    const float* __restrict__ A, const ushort* __restrict__ Bh,
    const ushort* __restrict__ Bl, const float* __restrict__ bias,
    float* __restrict__ H, float* __restrict__ z, int n) {
  constexpr int KC = K / 32;          // 32-k chunks
  constexpr int NTt = TN / 16;        // col tiles
  constexpr int HALF = K * TN / 8;    // int4s per (hi or lo) slab copy
  __shared__ int4 bsm[2 * HALF];
  const int tid = threadIdx.x;
  const int w = tid >> 6, lane = tid & 63;
  const int quad = lane >> 4, nn = lane & 15;
  const int rowBase = blockIdx.x * 64 + w * 16;

  // ---- load this wave's A fragments (16 rows), split hi/lo in-register ----
  int row = rowBase + nn;
  if (row >= n) row = n - 1;  // clamp; stores are guarded
  const float* ap = &A[(size_t)row * K + quad * 8];
  bf16x8 ah[KC], al[KC];
#pragma unroll
  for (int kc = 0; kc < KC; kc++) {
    float4 f0 = *(const float4*)(ap + kc * 32);
    float4 f1 = *(const float4*)(ap + kc * 32 + 4);
    float f[8] = {f0.x, f0.y, f0.z, f0.w, f1.x, f1.y, f1.z, f1.w};
#pragma unroll
    for (int j = 0; j < 8; j++) {
      unsigned short h = f2bf(f[j]);
      ah[kc][j] = (short)h;
      al[kc][j] = (short)f2bf(f[j] - bf2f(h));
    }
  }

  const short* bsp = (const short*)bsm;

#pragma unroll 1
  for (int slab = 0; slab < 4; slab++) {
    // stage B hi+lo for this slab into LDS
    __syncthreads();  // prior slab's reads done before overwrite
    {
      const int4* gh = (const int4*)(Bh + (size_t)slab * K * TN);
      const int4* gl = (const int4*)(Bl + (size_t)slab * K * TN);
      for (int i = tid; i < HALF; i += 256) {
        bsm[i] = gh[i];
        bsm[HALF + i] = gl[i];
      }
    }
    __syncthreads();

    f32x4 acc[NTt];
#pragma unroll
    for (int j = 0; j < NTt; j++) acc[j] = (f32x4){0.f, 0.f, 0.f, 0.f};

    // Ah*Bh + Al*Bh (Bh frag read once), then Ah*Bl
#pragma unroll
    for (int kc = 0; kc < KC; kc++) {
#pragma unroll
      for (int nt = 0; nt < NTt; nt++) {
        bf16x8 b = *(const bf16x8*)&bsp[((kc * NTt + nt) * 64 + lane) * 8];
        acc[nt] = __builtin_amdgcn_mfma_f32_16x16x32_bf16(ah[kc], b, acc[nt], 0, 0, 0);
        acc[nt] = __builtin_amdgcn_mfma_f32_16x16x32_bf16(al[kc], b, acc[nt], 0, 0, 0);
      }
    }
#pragma unroll
    for (int kc = 0; kc < KC; kc++) {
#pragma unroll
      for (int nt = 0; nt < NTt; nt++) {
        bf16x8 b = *(const bf16x8*)&bsp[(HALF * 8) + ((kc * NTt + nt) * 64 + lane) * 8];
        acc[nt] = __builtin_amdgcn_mfma_f32_16x16x32_bf16(ah[kc], b, acc[nt], 0, 0, 0);
      }
    }

    // epilogue: D row = quad*4+reg, col = lane&15 (m89-verified)
    int grow0 = rowBase + quad * 4;
#pragma unroll
    for (int nt = 0; nt < NTt; nt++) {
      int col = nt * 16 + nn;
#pragma unroll
      for (int rg = 0; rg < 4; rg++) {
        int grow = grow0 + rg;
        if (grow < n) {
          float v = acc[nt][rg];
          if (slab == 3) z[(size_t)grow * TN + col] = v + bias[col];
          else H[((size_t)slab * n + grow) * TN + col] = v;
        }
      }
    }
  }
}

// ---- pull, C=64: one wave per node; 16 lanes x float4 per edge, 4 edges/iter.
__global__ __launch_bounds__(256) void pull64_kernel(
    const float4* __restrict__ H4, const int* __restrict__ eSrcT,
    const int* __restrict__ startp, const int* __restrict__ deg,
    const float* __restrict__ inv, float* __restrict__ z, int N) {
  int w = (blockIdx.x * 256 + threadIdx.x) >> 6;
  if (w >= N) return;
  int lane = threadIdx.x & 63;
  int g = lane >> 4;
  int q = lane & 15;
  int st = startp[w];
  int dg = deg[w];
  float sc0 = inv[w], sc1 = inv[N + w], sc2 = inv[2 * N + w];
  float4 acc = make_float4(0.f, 0.f, 0.f, 0.f);
  for (int i = g; i < dg; i += 4) {
    int p = eSrcT[st + i];
    int s = p & 0xFFFFF;
    int t = p >> 20;
    float sc = (t == 0) ? sc0 : ((t == 1) ? sc1 : sc2);
    float4 v = H4[((size_t)t * N + s) * 16 + q];
    acc.x += v.x * sc; acc.y += v.y * sc; acc.z += v.z * sc; acc.w += v.w * sc;
  }
#pragma unroll
  for (int m = 16; m <= 32; m <<= 1) {
    acc.x += __shfl_xor(acc.x, m);
    acc.y += __shfl_xor(acc.y, m);
    acc.z += __shfl_xor(acc.z, m);
    acc.w += __shfl_xor(acc.w, m);
  }
  if (g == 0) {
    float4* zp = (float4*)z + (size_t)w * 16 + q;
    float4 zv = *zp;
    zv.x = fmaxf(zv.x + acc.x, 0.f);
    zv.y = fmaxf(zv.y + acc.y, 0.f);
    zv.z = fmaxf(zv.z + acc.z, 0.f);
    zv.w = fmaxf(zv.w + acc.w, 0.f);
    *zp = zv;
  }
}

// ---- pull, C=32: 8 lanes x float4 per edge, 8 edges/iter. No ReLU.
__global__ __launch_bounds__(256) void pull32_kernel(
    const float4* __restrict__ H4, const int* __restrict__ eSrcT,
    const int* __restrict__ startp, const int* __restrict__ deg,
    const float* __restrict__ inv, float* __restrict__ z, int N) {
  int w = (blockIdx.x * 256 + threadIdx.x) >> 6;
  if (w >= N) return;
  int lane = threadIdx.x & 63;
  int g = lane >> 3;
  int q = lane & 7;
  int st = startp[w];
  int dg = deg[w];
  float sc0 = inv[w], sc1 = inv[N + w], sc2 = inv[2 * N + w];
  float4 acc = make_float4(0.f, 0.f, 0.f, 0.f);
  for (int i = g; i < dg; i += 8) {
    int p = eSrcT[st + i];
    int s = p & 0xFFFFF;
    int t = p >> 20;
    float sc = (t == 0) ? sc0 : ((t == 1) ? sc1 : sc2);
    float4 v = H4[((size_t)t * N + s) * 8 + q];
    acc.x += v.x * sc; acc.y += v.y * sc; acc.z += v.z * sc; acc.w += v.w * sc;
  }
#pragma unroll
  for (int m = 8; m <= 32; m <<= 1) {
    acc.x += __shfl_xor(acc.x, m);
    acc.y += __shfl_xor(acc.y, m);
    acc.z += __shfl_xor(acc.z, m);
    acc.w += __shfl_xor(acc.w, m);
  }
  if (g == 0) {
    float4* zp = (float4*)z + (size_t)w * 8 + q;
    float4 zv = *zp;
    zv.x += acc.x; zv.y += acc.y; zv.z += acc.z; zv.w += acc.w;
    *zp = zv;
  }
}

// Decoder: one thread per pred edge. Wd1 broadcast from LDS.
__global__ __launch_bounds__(256) void decoder_kernel(
    const float* __restrict__ z, const int* __restrict__ pe,
    const float* __restrict__ Wd1, const float* __restrict__ bd1,
    const float* __restrict__ Wd2, const float* __restrict__ bd2,
    float* __restrict__ out, int P) {
  __shared__ float W[64 * 64];
  __shared__ float w2[64], b1s[64];
  int tid = threadIdx.x;
  for (int i = tid * 4; i < 4096; i += 1024) *(float4*)&W[i] = *(const float4*)&Wd1[i];
  if (tid < 64) {
    w2[tid] = Wd2[tid];
    b1s[tid] = bd1[tid];
  }
  __syncthreads();
  int p = blockIdx.x * 256 + tid;
  if (p >= P) return;
  int s = pe[p];
  int d = pe[P + p];
  float zs[32], zd[32];
  const float4* ps4 = (const float4*)&z[(size_t)s * 32];
  const float4* pd4 = (const float4*)&z[(size_t)d * 32];
#pragma unroll
  for (int i = 0; i < 8; i++) {
    float4 a = ps4[i];
    zs[4 * i] = a.x; zs[4 * i + 1] = a.y; zs[4 * i + 2] = a.z; zs[4 * i + 3] = a.w;
    float4 b = pd4[i];
    zd[4 * i] = b.x; zd[4 * i + 1] = b.y; zd[4 * i + 2] = b.z; zd[4 * i + 3] = b.w;
  }
  float acc = bd2[0];
#pragma unroll 4
  for (int j = 0; j < 64; j++) {
    float h = b1s[j];
#pragma unroll
    for (int i = 0; i < 32; i++) h += zs[i] * W[i * 64 + j];
#pragma unroll
    for (int i = 0; i < 32; i++) h += zd[i] * W[(32 + i) * 64 + j];
    h = fmaxf(h, 0.0f);
    acc += h * w2[j];
  }
  out[p] = acc;
}

extern "C" void kernel_launch(void* const* d_in, const int* in_sizes, int n_in,
                              void* d_out, int out_size, void* d_ws, size_t ws_size,
                              hipStream_t stream) {
  const float* x     = (const float*)d_in[0];
  const int*   ei    = (const int*)d_in[1];
  const int*   et    = (const int*)d_in[2];
  const int*   pe    = (const int*)d_in[3];
  const float* W1    = (const float*)d_in[4];
  const float* root1 = (const float*)d_in[5];
  const float* b1    = (const float*)d_in[6];
  const float* W2    = (const float*)d_in[7];
  const float* root2 = (const float*)d_in[8];
  const float* b2    = (const float*)d_in[9];
  const float* Wd1   = (const float*)d_in[10];
  const float* bd1   = (const float*)d_in[11];
  const float* Wd2   = (const float*)d_in[12];
  const float* bd2   = (const float*)d_in[13];
  float* out = (float*)d_out;

  const int N = in_sizes[0] / 128;  // 100000
  const int E = in_sizes[2];        // 1600000
  const int P = in_sizes[3] / 2;    // 200000

  const int NBUCK = (N + 511) >> 9;         // coarse buckets (dst>>9), <=256
  const int tile  = (E + 255) / 256;        // edges per partition block

  // Workspace layout (float units; all offsets 16B-aligned for even N):
  //   inv:0..4N  z1:4N..68N  z2:68N..100N  H:100N..292N  Bpack:292N..293N
  //   ints from 293N: deg N | startp N | bstart 1K | hist NBUCK*256 | rec 2E | eSrcT E
  float* ws  = (float*)d_ws;
  float* inv = ws;
  float* z1  = ws + (size_t)4 * N;
  float* z2  = ws + (size_t)68 * N;
  float* H   = ws + (size_t)100 * N;
  ushort* Bh1 = (ushort*)(ws + (size_t)292 * N);  // 4*128*64
  ushort* Bl1 = Bh1 + 32768;
  ushort* Bh2 = Bl1 + 32768;                      // 4*64*32
  ushort* Bl2 = Bh2 + 8192;
  int* ib     = (int*)(ws + (size_t)293 * N);
  int* deg    = ib;
  int* startp = ib + N;
  int* bstart = ib + 2 * (size_t)N;               // NBUCK+1 (pad to 1024)
  int* hist   = ib + 2 * (size_t)N + 1024;        // NBUCK*256
  size_t roff = 2 * (size_t)N + 1024 + (size_t)NBUCK * 256;
  roff = (roff + 3) & ~(size_t)3;                 // 16B align for uint2
  uint2* rec  = (uint2*)(ib + roff);              // E records
  int* eSrcT  = ib + roff + 2 * (size_t)E;        // E

  // --- CSR build: 2-level bucket sort, LDS atomics only ---
  part_hist_kernel<<<256, 256, 0, stream>>>(ei, hist, E, tile, NBUCK);
  part_scan_kernel<<<1, 256, 0, stream>>>(hist, bstart, NBUCK);
  part_scatter_kernel<<<256, 256, 0, stream>>>(ei, et, hist, rec, E, tile, NBUCK);
  bucket_build_kernel<<<NBUCK, 256, 0, stream>>>(rec, bstart, inv, deg, startp, eSrcT, N);

  // --- weight packing (tiny) ---
  packw_kernel<<<(4 * 128 * 64 + 255) / 256, 256, 0, stream>>>(W1, root1, Bh1, Bl1, 128, 64);
  packw_kernel<<<(4 * 64 * 32 + 255) / 256, 256, 0, stream>>>(W2, root2, Bh2, Bl2, 64, 32);

  const int gb = (N + 63) / 64;  // 1 block = 4 waves = 64 rows
  const int pullBlocks = (N * 64 + 255) / 256;

  // --- layer 1: K=128 -> 64 ---
  mfma_gemm_kernel<128, 64><<<gb, 256, 0, stream>>>(x, Bh1, Bl1, b1, H, z1, N);
  pull64_kernel<<<pullBlocks, 256, 0, stream>>>((const float4*)H, eSrcT, startp, deg, inv, z1, N);

  // --- layer 2: K=64 -> 32 ---
  mfma_gemm_kernel<64, 32><<<gb, 256, 0, stream>>>(z1, Bh2, Bl2, b2, H, z2, N);
  pull32_kernel<<<pullBlocks, 256, 0, stream>>>((const float4*)H, eSrcT, startp, deg, inv, z2, N);

  // --- decoder ---
  decoder_kernel<<<(P + 255) / 256, 256, 0, stream>>>(z2, pe, Wd1, bd1, Wd2, bd2, out, P);
}

// Round 8
// 392.847 us; speedup vs baseline: 1.1861x; 1.0667x over previous
//
#include <hip/hip_runtime.h>

// ---------------------------------------------------------------------------
// RGCN link predictor. Atomic-free CSR build + CSR-pull + split-bf16 MFMA GEMM.
//   rgcn_conv(x) = x@root + b + sum_r segsum_dst( H_r[src] ) / max(cnt_r[dst],1)
//   H (per-relation transformed nodes) stored in BF16: halves the random-gather
//   payload in the pull kernels (the measured wall) and H's cache footprint.
//   Root/bias path and all accumulation stay fp32.
//   GEMM: fp32 via bf16 split (Ah*Bh + Al*Bh + Ah*Bl), 1 m-tile/wave, B in LDS.
// ---------------------------------------------------------------------------

typedef short bf16x8 __attribute__((ext_vector_type(8)));
typedef float f32x4 __attribute__((ext_vector_type(4)));

__device__ __forceinline__ unsigned short f2bf(float f) {
  union { float f; unsigned u; } x; x.f = f;
  unsigned r = x.u + 0x7FFF + ((x.u >> 16) & 1);  // RNE
  return (unsigned short)(r >> 16);
}
__device__ __forceinline__ float bf2f(unsigned short h) {
  union { unsigned u; float f; } x; x.u = ((unsigned)h) << 16;
  return x.f;
}

// ---- level-1 partition: histogram of dst>>9 per block tile ----
__global__ __launch_bounds__(256) void part_hist_kernel(
    const int* __restrict__ ei, int* __restrict__ hist,
    int E, int tile, int NBUCK) {
  __shared__ int lh[256];
  int tid = threadIdx.x;
  lh[tid] = 0;
  __syncthreads();
  int e0 = blockIdx.x * tile;
  int e1 = min(E, e0 + tile);
  for (int e = e0 + tid; e < e1; e += 256) {
    int d = ei[E + e];
    atomicAdd(&lh[d >> 9], 1);
  }
  __syncthreads();
  if (tid < NBUCK) hist[tid * 256 + blockIdx.x] = lh[tid];
}

// scan hist rows (bucket-major) + bucket bases; rewrite hist to global cursors
__global__ __launch_bounds__(256) void part_scan_kernel(
    int* __restrict__ hist, int* __restrict__ bstart, int NBUCK) {
  __shared__ int sA[256], sB[256];
  int t = threadIdx.x;
  int tot = 0;
  if (t < NBUCK) {
    int* row = hist + t * 256;
    for (int i = 0; i < 256; i++) { int v = row[i]; row[i] = tot; tot += v; }
  }
  sA[t] = tot;
  __syncthreads();
  int* src = sA; int* dst = sB;
  for (int off = 1; off < 256; off <<= 1) {
    int v = src[t];
    if (t >= off) v += src[t - off];
    dst[t] = v;
    __syncthreads();
    int* tmp = src; src = dst; dst = tmp;
  }
  int base = src[t] - tot;  // exclusive
  if (t < NBUCK) {
    bstart[t] = base;
    int* row = hist + t * 256;
    for (int i = 0; i < 256; i++) row[i] += base;
    if (t == NBUCK - 1) bstart[NBUCK] = base + tot;
  }
}

// scatter edges into coarse buckets (LDS cursors, plain global stores)
__global__ __launch_bounds__(256) void part_scatter_kernel(
    const int* __restrict__ ei, const int* __restrict__ et,
    const int* __restrict__ hist, uint2* __restrict__ rec,
    int E, int tile, int NBUCK) {
  __shared__ int ctr[256];
  int tid = threadIdx.x;
  ctr[tid] = (tid < NBUCK) ? hist[tid * 256 + blockIdx.x] : 0;
  __syncthreads();
  int e0 = blockIdx.x * tile;
  int e1 = min(E, e0 + tile);
  for (int e = e0 + tid; e < e1; e += 256) {
    int s = ei[e];
    int d = ei[E + e];
    int t = et[e];
    int p = atomicAdd(&ctr[d >> 9], 1);
    rec[p] = make_uint2((unsigned)(s | (t << 20)), (unsigned)d);
  }
}

// ---- level-2: one block per bucket (dst window of 512). Produces per-(rel,dst)
// inv, deg, startp and the final dst-grouped eSrcT — LDS atomics only.
__global__ __launch_bounds__(256) void bucket_build_kernel(
    const uint2* __restrict__ rec, const int* __restrict__ bstart,
    float* __restrict__ inv, int* __restrict__ deg, int* __restrict__ startp,
    int* __restrict__ eSrcT, int N) {
  __shared__ int c3[1536];
  __shared__ int sA[512], sB[512];
  __shared__ int cur[512];
  int tid = threadIdx.x;
  int dstBase = blockIdx.x << 9;
  int bs = bstart[blockIdx.x], be = bstart[blockIdx.x + 1];
  for (int i = tid; i < 1536; i += 256) c3[i] = 0;
  __syncthreads();
  for (int i = bs + tid; i < be; i += 256) {
    uint2 r = rec[i];
    atomicAdd(&c3[(r.x >> 20) * 512 + (r.y & 511)], 1);
  }
  __syncthreads();
  for (int i = tid; i < 512; i += 256) {
    int d = dstBase + i;
    int c0 = c3[i], c1 = c3[512 + i], c2 = c3[1024 + i];
    int dg = c0 + c1 + c2;
    sA[i] = dg;
    if (d < N) {
      deg[d] = dg;
      inv[d]         = 1.0f / (float)max(c0, 1);
      inv[N + d]     = 1.0f / (float)max(c1, 1);
      inv[2 * N + d] = 1.0f / (float)max(c2, 1);
    }
  }
  __syncthreads();
  int* src = sA; int* dst = sB;
  for (int off = 1; off < 512; off <<= 1) {
    for (int i = tid; i < 512; i += 256) {
      int v = src[i];
      if (i >= off) v += src[i - off];
      dst[i] = v;
    }
    __syncthreads();
    int* tmp = src; src = dst; dst = tmp;
  }
  for (int i = tid; i < 512; i += 256) {
    int excl = (i > 0) ? src[i - 1] : 0;
    cur[i] = bs + excl;
    int d = dstBase + i;
    if (d < N) startp[d] = bs + excl;
  }
  __syncthreads();
  for (int i = bs + tid; i < be; i += 256) {
    uint2 r = rec[i];
    int p = atomicAdd(&cur[r.y & 511], 1);
    eSrcT[p] = (int)r.x;
  }
}

// pack weights (3 relation slabs + root) into MFMA B-fragment order, split hi/lo.
__global__ __launch_bounds__(256) void packw_kernel(
    const float* __restrict__ W, const float* __restrict__ root,
    ushort* __restrict__ Bh, ushort* __restrict__ Bl, int K, int TN) {
  int e = blockIdx.x * 256 + threadIdx.x;
  if (e >= 4 * K * TN) return;
  int slab = e / (K * TN), r = e % (K * TN);
  int k = r / TN, n = r % TN;
  float v = (slab < 3) ? W[(size_t)slab * K * TN + k * TN + n] : root[(size_t)k * TN + n];
  int kc = k >> 5, quad = (k >> 3) & 3, j = k & 7, nt = n >> 4, nn = n & 15;
  int NTt = TN / 16;
  int didx = slab * K * TN + ((kc * NTt + nt) * 64 + quad * 16 + nn) * 8 + j;
  unsigned short h = f2bf(v);
  Bh[didx] = h;
  Bl[didx] = f2bf(v - bf2f(h));
}

// Split-bf16 MFMA GEMM. Block = 4 waves x 16 rows = 64 rows.
// A-frag (m=lane&15, k=quad*8+j) = 8 contiguous row-major elems -> direct
// global->register, hi/lo split in-register. B (hi+lo) staged per-slab in LDS.
// slabs 0..2 -> Hb[slab] = bf16(A@W[slab]); slab 3 -> z = A@root + bias (fp32).
template <int K, int TN>
__global__ __launch_bounds__(256, 4) void mfma_gemm_kernel(
    const float* __restrict__ A, const ushort* __restrict__ Bh,
    const ushort* __restrict__ Bl, const float* __restrict__ bias,
    ushort* __restrict__ Hb, float* __restrict__ z, int n) {
  constexpr int KC = K / 32;          // 32-k chunks
  constexpr int NTt = TN / 16;        // col tiles
  constexpr int HALF = K * TN / 8;    // int4s per (hi or lo) slab copy
  __shared__ int4 bsm[2 * HALF];
  const int tid = threadIdx.x;
  const int w = tid >> 6, lane = tid & 63;
  const int quad = lane >> 4, nn = lane & 15;
  const int rowBase = blockIdx.x * 64 + w * 16;

  // ---- load this wave's A fragments (16 rows), split hi/lo in-register ----
  int row = rowBase + nn;
  if (row >= n) row = n - 1;  // clamp; stores are guarded
  const float* ap = &A[(size_t)row * K + quad * 8];
  bf16x8 ah[KC], al[KC];
#pragma unroll
  for (int kc = 0; kc < KC; kc++) {
    float4 f0 = *(const float4*)(ap + kc * 32);
    float4 f1 = *(const float4*)(ap + kc * 32 + 4);
    float f[8] = {f0.x, f0.y, f0.z, f0.w, f1.x, f1.y, f1.z, f1.w};
#pragma unroll
    for (int j = 0; j < 8; j++) {
      unsigned short h = f2bf(f[j]);
      ah[kc][j] = (short)h;
      al[kc][j] = (short)f2bf(f[j] - bf2f(h));
    }
  }

  const short* bsp = (const short*)bsm;

#pragma unroll 1
  for (int slab = 0; slab < 4; slab++) {
    // stage B hi+lo for this slab into LDS
    __syncthreads();  // prior slab's reads done before overwrite
    {
      const int4* gh = (const int4*)(Bh + (size_t)slab * K * TN);
      const int4* gl = (const int4*)(Bl + (size_t)slab * K * TN);
      for (int i = tid; i < HALF; i += 256) {
        bsm[i] = gh[i];
        bsm[HALF + i] = gl[i];
      }
    }
    __syncthreads();

    f32x4 acc[NTt];
#pragma unroll
    for (int j = 0; j < NTt; j++) acc[j] = (f32x4){0.f, 0.f, 0.f, 0.f};

    // Ah*Bh + Al*Bh (Bh frag read once), then Ah*Bl
#pragma unroll
    for (int kc = 0; kc < KC; kc++) {
#pragma unroll
      for (int nt = 0; nt < NTt; nt++) {
        bf16x8 b = *(const bf16x8*)&bsp[((kc * NTt + nt) * 64 + lane) * 8];
        acc[nt] = __builtin_amdgcn_mfma_f32_16x16x32_bf16(ah[kc], b, acc[nt], 0, 0, 0);
        acc[nt] = __builtin_amdgcn_mfma_f32_16x16x32_bf16(al[kc], b, acc[nt], 0, 0, 0);
      }
    }
#pragma unroll
    for (int kc = 0; kc < KC; kc++) {
#pragma unroll
      for (int nt = 0; nt < NTt; nt++) {
        bf16x8 b = *(const bf16x8*)&bsp[(HALF * 8) + ((kc * NTt + nt) * 64 + lane) * 8];
        acc[nt] = __builtin_amdgcn_mfma_f32_16x16x32_bf16(ah[kc], b, acc[nt], 0, 0, 0);
      }
    }

    // epilogue: D row = quad*4+reg, col = lane&15 (m89-verified)
    int grow0 = rowBase + quad * 4;
#pragma unroll
    for (int nt = 0; nt < NTt; nt++) {
      int col = nt * 16 + nn;
#pragma unroll
      for (int rg = 0; rg < 4; rg++) {
        int grow = grow0 + rg;
        if (grow < n) {
          float v = acc[nt][rg];
          if (slab == 3) z[(size_t)grow * TN + col] = v + bias[col];
          else Hb[((size_t)slab * n + grow) * TN + col] = f2bf(v);
        }
      }
    }
  }
}

// ---- pull, C=64 bf16 H: one wave per node; 8 lanes x 16B per edge,
// 8 edges in flight. Fuses root add + ReLU. z stays fp32.
__global__ __launch_bounds__(256) void pull64_kernel(
    const ushort* __restrict__ Hb, const int* __restrict__ eSrcT,
    const int* __restrict__ startp, const int* __restrict__ deg,
    const float* __restrict__ inv, float* __restrict__ z, int N) {
  int w = (blockIdx.x * 256 + threadIdx.x) >> 6;
  if (w >= N) return;
  int lane = threadIdx.x & 63;
  int g = lane >> 3;  // edge group 0..7
  int q = lane & 7;   // 8-channel chunk
  int st = startp[w];
  int dg = deg[w];
  float sc0 = inv[w], sc1 = inv[N + w], sc2 = inv[2 * N + w];
  float acc[8] = {0.f, 0.f, 0.f, 0.f, 0.f, 0.f, 0.f, 0.f};
  for (int i = g; i < dg; i += 8) {
    int p = eSrcT[st + i];
    int s = p & 0xFFFFF;
    int t = p >> 20;
    float sc = (t == 0) ? sc0 : ((t == 1) ? sc1 : sc2);
    uint4 v = *(const uint4*)&Hb[((size_t)t * N + s) * 64 + q * 8];
    unsigned uu[4] = {v.x, v.y, v.z, v.w};
    union { unsigned u; float f; } c;
#pragma unroll
    for (int j = 0; j < 4; j++) {
      c.u = uu[j] << 16;         acc[2 * j]     += c.f * sc;
      c.u = uu[j] & 0xFFFF0000u; acc[2 * j + 1] += c.f * sc;
    }
  }
#pragma unroll
  for (int m = 8; m <= 32; m <<= 1)
#pragma unroll
    for (int j = 0; j < 8; j++) acc[j] += __shfl_xor(acc[j], m);
  if (g == 0) {
    float4* zp = (float4*)&z[(size_t)w * 64 + q * 8];
    float4 a = zp[0], b = zp[1];
    a.x = fmaxf(a.x + acc[0], 0.f); a.y = fmaxf(a.y + acc[1], 0.f);
    a.z = fmaxf(a.z + acc[2], 0.f); a.w = fmaxf(a.w + acc[3], 0.f);
    b.x = fmaxf(b.x + acc[4], 0.f); b.y = fmaxf(b.y + acc[5], 0.f);
    b.z = fmaxf(b.z + acc[6], 0.f); b.w = fmaxf(b.w + acc[7], 0.f);
    zp[0] = a; zp[1] = b;
  }
}

// ---- pull, C=32 bf16 H: 4 lanes x 16B per edge, 16 edges in flight. No ReLU.
__global__ __launch_bounds__(256) void pull32_kernel(
    const ushort* __restrict__ Hb, const int* __restrict__ eSrcT,
    const int* __restrict__ startp, const int* __restrict__ deg,
    const float* __restrict__ inv, float* __restrict__ z, int N) {
  int w = (blockIdx.x * 256 + threadIdx.x) >> 6;
  if (w >= N) return;
  int lane = threadIdx.x & 63;
  int g = lane >> 2;  // edge group 0..15
  int q = lane & 3;   // 8-channel chunk
  int st = startp[w];
  int dg = deg[w];
  float sc0 = inv[w], sc1 = inv[N + w], sc2 = inv[2 * N + w];
  float acc[8] = {0.f, 0.f, 0.f, 0.f, 0.f, 0.f, 0.f, 0.f};
  for (int i = g; i < dg; i += 16) {
    int p = eSrcT[st + i];
    int s = p & 0xFFFFF;
    int t = p >> 20;
    float sc = (t == 0) ? sc0 : ((t == 1) ? sc1 : sc2);
    uint4 v = *(const uint4*)&Hb[((size_t)t * N + s) * 32 + q * 8];
    unsigned uu[4] = {v.x, v.y, v.z, v.w};
    union { unsigned u; float f; } c;
#pragma unroll
    for (int j = 0; j < 4; j++) {
      c.u = uu[j] << 16;         acc[2 * j]     += c.f * sc;
      c.u = uu[j] & 0xFFFF0000u; acc[2 * j + 1] += c.f * sc;
    }
  }
#pragma unroll
  for (int m = 4; m <= 32; m <<= 1)
#pragma unroll
    for (int j = 0; j < 8; j++) acc[j] += __shfl_xor(acc[j], m);
  if (g == 0) {
    float4* zp = (float4*)&z[(size_t)w * 32 + q * 8];
    float4 a = zp[0], b = zp[1];
    a.x += acc[0]; a.y += acc[1]; a.z += acc[2]; a.w += acc[3];
    b.x += acc[4]; b.y += acc[5]; b.z += acc[6]; b.w += acc[7];
    zp[0] = a; zp[1] = b;
  }
}

// Decoder: one thread per pred edge. Wd1 broadcast from LDS.
__global__ __launch_bounds__(256) void decoder_kernel(
    const float* __restrict__ z, const int* __restrict__ pe,
    const float* __restrict__ Wd1, const float* __restrict__ bd1,
    const float* __restrict__ Wd2, const float* __restrict__ bd2,
    float* __restrict__ out, int P) {
  __shared__ float W[64 * 64];
  __shared__ float w2[64], b1s[64];
  int tid = threadIdx.x;
  for (int i = tid * 4; i < 4096; i += 1024) *(float4*)&W[i] = *(const float4*)&Wd1[i];
  if (tid < 64) {
    w2[tid] = Wd2[tid];
    b1s[tid] = bd1[tid];
  }
  __syncthreads();
  int p = blockIdx.x * 256 + tid;
  if (p >= P) return;
  int s = pe[p];
  int d = pe[P + p];
  float zs[32], zd[32];
  const float4* ps4 = (const float4*)&z[(size_t)s * 32];
  const float4* pd4 = (const float4*)&z[(size_t)d * 32];
#pragma unroll
  for (int i = 0; i < 8; i++) {
    float4 a = ps4[i];
    zs[4 * i] = a.x; zs[4 * i + 1] = a.y; zs[4 * i + 2] = a.z; zs[4 * i + 3] = a.w;
    float4 b = pd4[i];
    zd[4 * i] = b.x; zd[4 * i + 1] = b.y; zd[4 * i + 2] = b.z; zd[4 * i + 3] = b.w;
  }
  float acc = bd2[0];
#pragma unroll 4
  for (int j = 0; j < 64; j++) {
    float h = b1s[j];
#pragma unroll
    for (int i = 0; i < 32; i++) h += zs[i] * W[i * 64 + j];
#pragma unroll
    for (int i = 0; i < 32; i++) h += zd[i] * W[(32 + i) * 64 + j];
    h = fmaxf(h, 0.0f);
    acc += h * w2[j];
  }
  out[p] = acc;
}

extern "C" void kernel_launch(void* const* d_in, const int* in_sizes, int n_in,
                              void* d_out, int out_size, void* d_ws, size_t ws_size,
                              hipStream_t stream) {
  const float* x     = (const float*)d_in[0];
  const int*   ei    = (const int*)d_in[1];
  const int*   et    = (const int*)d_in[2];
  const int*   pe    = (const int*)d_in[3];
  const float* W1    = (const float*)d_in[4];
  const float* root1 = (const float*)d_in[5];
  const float* b1    = (const float*)d_in[6];
  const float* W2    = (const float*)d_in[7];
  const float* root2 = (const float*)d_in[8];
  const float* b2    = (const float*)d_in[9];
  const float* Wd1   = (const float*)d_in[10];
  const float* bd1   = (const float*)d_in[11];
  const float* Wd2   = (const float*)d_in[12];
  const float* bd2   = (const float*)d_in[13];
  float* out = (float*)d_out;

  const int N = in_sizes[0] / 128;  // 100000
  const int E = in_sizes[2];        // 1600000
  const int P = in_sizes[3] / 2;    // 200000

  const int NBUCK = (N + 511) >> 9;         // coarse buckets (dst>>9), <=256
  const int tile  = (E + 255) / 256;        // edges per partition block

  // Workspace layout (float units; all offsets 16B-aligned for even N):
  //   inv:0..4N  z1:4N..68N  z2:68N..100N  Hb(bf16):100N..196N  Bpack:292N..293N
  //   ints from 293N: deg N | startp N | bstart 1K | hist NBUCK*256 | rec 2E | eSrcT E
  float* ws  = (float*)d_ws;
  float* inv = ws;
  float* z1  = ws + (size_t)4 * N;
  float* z2  = ws + (size_t)68 * N;
  ushort* Hb = (ushort*)(ws + (size_t)100 * N);   // 3*N*64 bf16 (layer1) / 3*N*32 (layer2)
  ushort* Bh1 = (ushort*)(ws + (size_t)292 * N);  // 4*128*64
  ushort* Bl1 = Bh1 + 32768;
  ushort* Bh2 = Bl1 + 32768;                      // 4*64*32
  ushort* Bl2 = Bh2 + 8192;
  int* ib     = (int*)(ws + (size_t)293 * N);
  int* deg    = ib;
  int* startp = ib + N;
  int* bstart = ib + 2 * (size_t)N;               // NBUCK+1 (pad to 1024)
  int* hist   = ib + 2 * (size_t)N + 1024;        // NBUCK*256
  size_t roff = 2 * (size_t)N + 1024 + (size_t)NBUCK * 256;
  roff = (roff + 3) & ~(size_t)3;                 // 16B align for uint2
  uint2* rec  = (uint2*)(ib + roff);              // E records
  int* eSrcT  = ib + roff + 2 * (size_t)E;        // E

  // --- CSR build: 2-level bucket sort, LDS atomics only ---
  part_hist_kernel<<<256, 256, 0, stream>>>(ei, hist, E, tile, NBUCK);
  part_scan_kernel<<<1, 256, 0, stream>>>(hist, bstart, NBUCK);
  part_scatter_kernel<<<256, 256, 0, stream>>>(ei, et, hist, rec, E, tile, NBUCK);
  bucket_build_kernel<<<NBUCK, 256, 0, stream>>>(rec, bstart, inv, deg, startp, eSrcT, N);

  // --- weight packing (tiny) ---
  packw_kernel<<<(4 * 128 * 64 + 255) / 256, 256, 0, stream>>>(W1, root1, Bh1, Bl1, 128, 64);
  packw_kernel<<<(4 * 64 * 32 + 255) / 256, 256, 0, stream>>>(W2, root2, Bh2, Bl2, 64, 32);

  const int gb = (N + 63) / 64;  // 1 block = 4 waves = 64 rows
  const int pullBlocks = (N * 64 + 255) / 256;

  // --- layer 1: K=128 -> 64 ---
  mfma_gemm_kernel<128, 64><<<gb, 256, 0, stream>>>(x, Bh1, Bl1, b1, Hb, z1, N);
  pull64_kernel<<<pullBlocks, 256, 0, stream>>>(Hb, eSrcT, startp, deg, inv, z1, N);

  // --- layer 2: K=64 -> 32 ---
  mfma_gemm_kernel<64, 32><<<gb, 256, 0, stream>>>(z1, Bh2, Bl2, b2, Hb, z2, N);
  pull32_kernel<<<pullBlocks, 256, 0, stream>>>(Hb, eSrcT, startp, deg, inv, z2, N);

  // --- decoder ---
  decoder_kernel<<<(P + 255) / 256, 256, 0, stream>>>(z2, pe, Wd1, bd1, Wd2, bd2, out, P);
}

// Round 9
// 370.818 us; speedup vs baseline: 1.2565x; 1.0594x over previous
//
#include <hip/hip_runtime.h>
#include <hip/hip_bf16.h>

// ---------------------------------------------------------------------------
// RGCN link predictor. Atomic-free CSR build + CSR-pull + split-bf16 MFMA GEMM.
//   rgcn_conv(x) = x@root + b + sum_r segsum_dst( H_r[src] ) / max(cnt_r[dst],1)
//   H stored bf16 (halves gather payload; error below threshold).
//   CSR: 2-level bucket sort by dst, 1-uint records (s|t<<20|(d&511)<<22),
//   LDS-local returning atomics only.
//   GEMM: H slabs 2-pass split (Ah*Bh+Al*Bh; dropped Ah*Bl is below bf16-H
//   quantization), z/root slab full 3-pass fp32.
// ---------------------------------------------------------------------------

typedef short bf16x8 __attribute__((ext_vector_type(8)));
typedef float f32x4 __attribute__((ext_vector_type(4)));

__device__ __forceinline__ unsigned short f2bf(float f) {
  union { float f; unsigned u; } x; x.f = f;
  unsigned r = x.u + 0x7FFF + ((x.u >> 16) & 1);  // RNE
  return (unsigned short)(r >> 16);
}
__device__ __forceinline__ float bf2f(unsigned short h) {
  union { unsigned u; float f; } x; x.u = ((unsigned)h) << 16;
  return x.f;
}
__device__ __forceinline__ float2 bf2x2(unsigned u) {
  union { unsigned u; __hip_bfloat162 h; } cv; cv.u = u;
  return __bfloat1622float2(cv.h);  // .x = low half, .y = high half
}

// ---- level-1 partition: histogram of dst>>9 per block tile ----
__global__ __launch_bounds__(256) void part_hist_kernel(
    const int* __restrict__ ei, int* __restrict__ hist,
    int E, int tile, int NBUCK) {
  __shared__ int lh[256];
  int tid = threadIdx.x;
  lh[tid] = 0;
  __syncthreads();
  int e0 = blockIdx.x * tile;
  int e1 = min(E, e0 + tile);
  for (int e = e0 + tid; e < e1; e += 256) {
    int d = ei[E + e];
    atomicAdd(&lh[d >> 9], 1);
  }
  __syncthreads();
  if (tid < NBUCK) hist[tid * 256 + blockIdx.x] = lh[tid];
}

// scan hist rows (bucket-major) + bucket bases; rewrite hist to global cursors
__global__ __launch_bounds__(256) void part_scan_kernel(
    int* __restrict__ hist, int* __restrict__ bstart, int NBUCK) {
  __shared__ int sA[256], sB[256];
  int t = threadIdx.x;
  int tot = 0;
  if (t < NBUCK) {
    int* row = hist + t * 256;
    for (int i = 0; i < 256; i++) { int v = row[i]; row[i] = tot; tot += v; }
  }
  sA[t] = tot;
  __syncthreads();
  int* src = sA; int* dst = sB;
  for (int off = 1; off < 256; off <<= 1) {
    int v = src[t];
    if (t >= off) v += src[t - off];
    dst[t] = v;
    __syncthreads();
    int* tmp = src; src = dst; dst = tmp;
  }
  int base = src[t] - tot;  // exclusive
  if (t < NBUCK) {
    bstart[t] = base;
    int* row = hist + t * 256;
    for (int i = 0; i < 256; i++) row[i] += base;
    if (t == NBUCK - 1) bstart[NBUCK] = base + tot;
  }
}

// scatter edges into coarse buckets (LDS cursors, plain 4B global stores)
__global__ __launch_bounds__(256) void part_scatter_kernel(
    const int* __restrict__ ei, const int* __restrict__ et,
    const int* __restrict__ hist, unsigned* __restrict__ rec,
    int E, int tile, int NBUCK) {
  __shared__ int ctr[256];
  int tid = threadIdx.x;
  ctr[tid] = (tid < NBUCK) ? hist[tid * 256 + blockIdx.x] : 0;
  __syncthreads();
  int e0 = blockIdx.x * tile;
  int e1 = min(E, e0 + tile);
  for (int e = e0 + tid; e < e1; e += 256) {
    int s = ei[e];
    int d = ei[E + e];
    int t = et[e];
    int p = atomicAdd(&ctr[d >> 9], 1);
    rec[p] = (unsigned)(s | (t << 20) | ((d & 511) << 22));
  }
}

// ---- level-2: one block per bucket (dst window of 512). Produces packed
// sd (start,deg), inv4 and the final dst-grouped eSrcT — LDS atomics only.
__global__ __launch_bounds__(256) void bucket_build_kernel(
    const unsigned* __restrict__ rec, const int* __restrict__ bstart,
    float4* __restrict__ inv4, int2* __restrict__ sd,
    int* __restrict__ eSrcT, int N) {
  __shared__ int c3[1536];
  __shared__ int sA[512], sB[512];
  __shared__ int cur[512];
  int tid = threadIdx.x;
  int dstBase = blockIdx.x << 9;
  int bs = bstart[blockIdx.x], be = bstart[blockIdx.x + 1];
  for (int i = tid; i < 1536; i += 256) c3[i] = 0;
  __syncthreads();
  for (int i = bs + tid; i < be; i += 256) {
    unsigned r = rec[i];
    atomicAdd(&c3[((r >> 20) & 3) * 512 + (r >> 22)], 1);
  }
  __syncthreads();
  for (int i = tid; i < 512; i += 256) {
    int c0 = c3[i], c1 = c3[512 + i], c2 = c3[1024 + i];
    sA[i] = c0 + c1 + c2;
    if (dstBase + i < N) {
      inv4[dstBase + i] = make_float4(1.0f / (float)max(c0, 1),
                                      1.0f / (float)max(c1, 1),
                                      1.0f / (float)max(c2, 1), 0.f);
    }
  }
  __syncthreads();
  int* src = sA; int* dst = sB;
  for (int off = 1; off < 512; off <<= 1) {
    for (int i = tid; i < 512; i += 256) {
      int v = src[i];
      if (i >= off) v += src[i - off];
      dst[i] = v;
    }
    __syncthreads();
    int* tmp = src; src = dst; dst = tmp;
  }
  for (int i = tid; i < 512; i += 256) {
    int excl = (i > 0) ? src[i - 1] : 0;
    int dg = src[i] - excl;
    cur[i] = bs + excl;
    if (dstBase + i < N) sd[dstBase + i] = make_int2(bs + excl, dg);
  }
  __syncthreads();
  for (int i = bs + tid; i < be; i += 256) {
    unsigned r = rec[i];
    int p = atomicAdd(&cur[r >> 22], 1);
    eSrcT[p] = (int)(r & 0x3FFFFF);  // s | t<<20
  }
}

// pack weights into MFMA B-fragment order, split hi/lo. Both layers, one grid.
template <int K, int TN>
__device__ __forceinline__ void pack_one(
    int e, const float* __restrict__ W, const float* __restrict__ root,
    ushort* __restrict__ Bh, ushort* __restrict__ Bl) {
  int slab = e / (K * TN), r = e % (K * TN);
  int k = r / TN, n = r % TN;
  float v = (slab < 3) ? W[(size_t)slab * K * TN + k * TN + n] : root[(size_t)k * TN + n];
  int kc = k >> 5, quad = (k >> 3) & 3, j = k & 7, nt = n >> 4, nn = n & 15;
  int NTt = TN / 16;
  int didx = slab * K * TN + ((kc * NTt + nt) * 64 + quad * 16 + nn) * 8 + j;
  unsigned short h = f2bf(v);
  Bh[didx] = h;
  Bl[didx] = f2bf(v - bf2f(h));
}

__global__ __launch_bounds__(256) void packw2_kernel(
    const float* __restrict__ W1, const float* __restrict__ root1,
    ushort* __restrict__ Bh1, ushort* __restrict__ Bl1,
    const float* __restrict__ W2, const float* __restrict__ root2,
    ushort* __restrict__ Bh2, ushort* __restrict__ Bl2) {
  int e = blockIdx.x * 256 + threadIdx.x;
  if (e < 32768) pack_one<128, 64>(e, W1, root1, Bh1, Bl1);
  else if (e < 32768 + 8192) pack_one<64, 32>(e - 32768, W2, root2, Bh2, Bl2);
}

// Split-bf16 MFMA GEMM. Block = 4 waves x 16 rows = 64 rows.
// A-frag direct global->register, hi/lo split in-register. B staged in LDS.
// H slabs (0-2): 2-pass (Ah*Bh + Al*Bh), output bf16 — dropped Ah*Bl is below
// the bf16 output quantization. z slab (3): 3-pass, fp32 + bias.
template <int K, int TN>
__global__ __launch_bounds__(256, 4) void mfma_gemm_kernel(
    const float* __restrict__ A, const ushort* __restrict__ Bh,
    const ushort* __restrict__ Bl, const float* __restrict__ bias,
    ushort* __restrict__ Hb, float* __restrict__ z, int n) {
  constexpr int KC = K / 32;          // 32-k chunks
  constexpr int NTt = TN / 16;        // col tiles
  constexpr int HALF = K * TN / 8;    // int4s per (hi or lo) slab copy
  __shared__ int4 bsm[2 * HALF];
  const int tid = threadIdx.x;
  const int w = tid >> 6, lane = tid & 63;
  const int quad = lane >> 4, nn = lane & 15;
  const int rowBase = blockIdx.x * 64 + w * 16;

  // ---- load this wave's A fragments (16 rows), split hi/lo in-register ----
  int row = rowBase + nn;
  if (row >= n) row = n - 1;  // clamp; stores are guarded
  const float* ap = &A[(size_t)row * K + quad * 8];
  bf16x8 ah[KC], al[KC];
#pragma unroll
  for (int kc = 0; kc < KC; kc++) {
    float4 f0 = *(const float4*)(ap + kc * 32);
    float4 f1 = *(const float4*)(ap + kc * 32 + 4);
    float f[8] = {f0.x, f0.y, f0.z, f0.w, f1.x, f1.y, f1.z, f1.w};
#pragma unroll
    for (int j = 0; j < 8; j++) {
      unsigned short h = f2bf(f[j]);
      ah[kc][j] = (short)h;
      al[kc][j] = (short)f2bf(f[j] - bf2f(h));
    }
  }

  const short* bsp = (const short*)bsm;

#pragma unroll 1
  for (int slab = 0; slab < 4; slab++) {
    // stage B for this slab into LDS (Bl only needed for slab 3)
    __syncthreads();  // prior slab's reads done before overwrite
    {
      const int4* gh = (const int4*)(Bh + (size_t)slab * K * TN);
      for (int i = tid; i < HALF; i += 256) bsm[i] = gh[i];
      if (slab == 3) {
        const int4* gl = (const int4*)(Bl + (size_t)slab * K * TN);
        for (int i = tid; i < HALF; i += 256) bsm[HALF + i] = gl[i];
      }
    }
    __syncthreads();

    f32x4 acc[NTt];
#pragma unroll
    for (int j = 0; j < NTt; j++) acc[j] = (f32x4){0.f, 0.f, 0.f, 0.f};

    // Ah*Bh + Al*Bh (Bh frag read once)
#pragma unroll
    for (int kc = 0; kc < KC; kc++) {
#pragma unroll
      for (int nt = 0; nt < NTt; nt++) {
        bf16x8 b = *(const bf16x8*)&bsp[((kc * NTt + nt) * 64 + lane) * 8];
        acc[nt] = __builtin_amdgcn_mfma_f32_16x16x32_bf16(ah[kc], b, acc[nt], 0, 0, 0);
        acc[nt] = __builtin_amdgcn_mfma_f32_16x16x32_bf16(al[kc], b, acc[nt], 0, 0, 0);
      }
    }
    if (slab == 3) {  // + Ah*Bl for the fp32 root path
#pragma unroll
      for (int kc = 0; kc < KC; kc++) {
#pragma unroll
        for (int nt = 0; nt < NTt; nt++) {
          bf16x8 b = *(const bf16x8*)&bsp[(HALF * 8) + ((kc * NTt + nt) * 64 + lane) * 8];
          acc[nt] = __builtin_amdgcn_mfma_f32_16x16x32_bf16(ah[kc], b, acc[nt], 0, 0, 0);
        }
      }
    }

    // epilogue: D row = quad*4+reg, col = lane&15 (m89-verified)
    int grow0 = rowBase + quad * 4;
#pragma unroll
    for (int nt = 0; nt < NTt; nt++) {
      int col = nt * 16 + nn;
#pragma unroll
      for (int rg = 0; rg < 4; rg++) {
        int grow = grow0 + rg;
        if (grow < n) {
          float v = acc[nt][rg];
          if (slab == 3) z[(size_t)grow * TN + col] = v + bias[col];
          else Hb[((size_t)slab * n + grow) * TN + col] = f2bf(v);
        }
      }
    }
  }
}

// ---- pull, C=64 bf16 H: one wave per node; 8 lanes x 16B per edge,
// 8 edges in flight. Fuses root add + ReLU. z stays fp32.
__global__ __launch_bounds__(256) void pull64_kernel(
    const ushort* __restrict__ Hb, const int* __restrict__ eSrcT,
    const int2* __restrict__ sd, const float4* __restrict__ inv4,
    float* __restrict__ z, int N) {
  int w = (blockIdx.x * 256 + threadIdx.x) >> 6;
  if (w >= N) return;
  int lane = threadIdx.x & 63;
  int g = lane >> 3;  // edge group 0..7
  int q = lane & 7;   // 8-channel chunk
  int2 sdv = sd[w];
  int st = sdv.x, dg = sdv.y;
  float4 iv = inv4[w];
  float acc[8] = {0.f, 0.f, 0.f, 0.f, 0.f, 0.f, 0.f, 0.f};
  for (int i = g; i < dg; i += 8) {
    int p = eSrcT[st + i];
    int s = p & 0xFFFFF;
    int t = p >> 20;
    float sc = (t == 0) ? iv.x : ((t == 1) ? iv.y : iv.z);
    uint4 v = *(const uint4*)&Hb[((size_t)t * N + s) * 64 + q * 8];
    float2 f0 = bf2x2(v.x), f1 = bf2x2(v.y), f2 = bf2x2(v.z), f3 = bf2x2(v.w);
    acc[0] += f0.x * sc; acc[1] += f0.y * sc;
    acc[2] += f1.x * sc; acc[3] += f1.y * sc;
    acc[4] += f2.x * sc; acc[5] += f2.y * sc;
    acc[6] += f3.x * sc; acc[7] += f3.y * sc;
  }
#pragma unroll
  for (int m = 8; m <= 32; m <<= 1)
#pragma unroll
    for (int j = 0; j < 8; j++) acc[j] += __shfl_xor(acc[j], m);
  if (g == 0) {
    float4* zp = (float4*)&z[(size_t)w * 64 + q * 8];
    float4 a = zp[0], b = zp[1];
    a.x = fmaxf(a.x + acc[0], 0.f); a.y = fmaxf(a.y + acc[1], 0.f);
    a.z = fmaxf(a.z + acc[2], 0.f); a.w = fmaxf(a.w + acc[3], 0.f);
    b.x = fmaxf(b.x + acc[4], 0.f); b.y = fmaxf(b.y + acc[5], 0.f);
    b.z = fmaxf(b.z + acc[6], 0.f); b.w = fmaxf(b.w + acc[7], 0.f);
    zp[0] = a; zp[1] = b;
  }
}

// ---- pull, C=32 bf16 H: 4 lanes x 16B per edge, 16 edges in flight. No ReLU.
__global__ __launch_bounds__(256) void pull32_kernel(
    const ushort* __restrict__ Hb, const int* __restrict__ eSrcT,
    const int2* __restrict__ sd, const float4* __restrict__ inv4,
    float* __restrict__ z, int N) {
  int w = (blockIdx.x * 256 + threadIdx.x) >> 6;
  if (w >= N) return;
  int lane = threadIdx.x & 63;
  int g = lane >> 2;  // edge group 0..15
  int q = lane & 3;   // 8-channel chunk
  int2 sdv = sd[w];
  int st = sdv.x, dg = sdv.y;
  float4 iv = inv4[w];
  float acc[8] = {0.f, 0.f, 0.f, 0.f, 0.f, 0.f, 0.f, 0.f};
  for (int i = g; i < dg; i += 16) {
    int p = eSrcT[st + i];
    int s = p & 0xFFFFF;
    int t = p >> 20;
    float sc = (t == 0) ? iv.x : ((t == 1) ? iv.y : iv.z);
    uint4 v = *(const uint4*)&Hb[((size_t)t * N + s) * 32 + q * 8];
    float2 f0 = bf2x2(v.x), f1 = bf2x2(v.y), f2 = bf2x2(v.z), f3 = bf2x2(v.w);
    acc[0] += f0.x * sc; acc[1] += f0.y * sc;
    acc[2] += f1.x * sc; acc[3] += f1.y * sc;
    acc[4] += f2.x * sc; acc[5] += f2.y * sc;
    acc[6] += f3.x * sc; acc[7] += f3.y * sc;
  }
#pragma unroll
  for (int m = 4; m <= 32; m <<= 1)
#pragma unroll
    for (int j = 0; j < 8; j++) acc[j] += __shfl_xor(acc[j], m);
  if (g == 0) {
    float4* zp = (float4*)&z[(size_t)w * 32 + q * 8];
    float4 a = zp[0], b = zp[1];
    a.x += acc[0]; a.y += acc[1]; a.z += acc[2]; a.w += acc[3];
    b.x += acc[4]; b.y += acc[5]; b.z += acc[6]; b.w += acc[7];
    zp[0] = a; zp[1] = b;
  }
}

// Decoder: one thread per pred edge. Wd1 broadcast from LDS.
__global__ __launch_bounds__(256) void decoder_kernel(
    const float* __restrict__ z, const int* __restrict__ pe,
    const float* __restrict__ Wd1, const float* __restrict__ bd1,
    const float* __restrict__ Wd2, const float* __restrict__ bd2,
    float* __restrict__ out, int P) {
  __shared__ float W[64 * 64];
  __shared__ float w2[64], b1s[64];
  int tid = threadIdx.x;
  for (int i = tid * 4; i < 4096; i += 1024) *(float4*)&W[i] = *(const float4*)&Wd1[i];
  if (tid < 64) {
    w2[tid] = Wd2[tid];
    b1s[tid] = bd1[tid];
  }
  __syncthreads();
  int p = blockIdx.x * 256 + tid;
  if (p >= P) return;
  int s = pe[p];
  int d = pe[P + p];
  float zs[32], zd[32];
  const float4* ps4 = (const float4*)&z[(size_t)s * 32];
  const float4* pd4 = (const float4*)&z[(size_t)d * 32];
#pragma unroll
  for (int i = 0; i < 8; i++) {
    float4 a = ps4[i];
    zs[4 * i] = a.x; zs[4 * i + 1] = a.y; zs[4 * i + 2] = a.z; zs[4 * i + 3] = a.w;
    float4 b = pd4[i];
    zd[4 * i] = b.x; zd[4 * i + 1] = b.y; zd[4 * i + 2] = b.z; zd[4 * i + 3] = b.w;
  }
  float acc = bd2[0];
#pragma unroll 4
  for (int j = 0; j < 64; j++) {
    float h = b1s[j];
#pragma unroll
    for (int i = 0; i < 32; i++) h += zs[i] * W[i * 64 + j];
#pragma unroll
    for (int i = 0; i < 32; i++) h += zd[i] * W[(32 + i) * 64 + j];
    h = fmaxf(h, 0.0f);
    acc += h * w2[j];
  }
  out[p] = acc;
}

extern "C" void kernel_launch(void* const* d_in, const int* in_sizes, int n_in,
                              void* d_out, int out_size, void* d_ws, size_t ws_size,
                              hipStream_t stream) {
  const float* x     = (const float*)d_in[0];
  const int*   ei    = (const int*)d_in[1];
  const int*   et    = (const int*)d_in[2];
  const int*   pe    = (const int*)d_in[3];
  const float* W1    = (const float*)d_in[4];
  const float* root1 = (const float*)d_in[5];
  const float* b1    = (const float*)d_in[6];
  const float* W2    = (const float*)d_in[7];
  const float* root2 = (const float*)d_in[8];
  const float* b2    = (const float*)d_in[9];
  const float* Wd1   = (const float*)d_in[10];
  const float* bd1   = (const float*)d_in[11];
  const float* Wd2   = (const float*)d_in[12];
  const float* bd2   = (const float*)d_in[13];
  float* out = (float*)d_out;

  const int N = in_sizes[0] / 128;  // 100000
  const int E = in_sizes[2];        // 1600000
  const int P = in_sizes[3] / 2;    // 200000

  const int NBUCK = (N + 511) >> 9;         // coarse buckets (dst>>9), <=256
  const int tile  = (E + 255) / 256;        // edges per partition block

  // Workspace layout (float units; all offsets 16B-aligned for even N):
  //   inv4:0..4N  z1:4N..68N  z2:68N..100N  Hb(bf16):100N..196N  Bpack:292N..293N
  //   ints from 293N: sd 2N | bstart 1K | hist NBUCK*256 | rec E | eSrcT E
  float* ws  = (float*)d_ws;
  float4* inv4 = (float4*)ws;                     // N float4
  float* z1  = ws + (size_t)4 * N;
  float* z2  = ws + (size_t)68 * N;
  ushort* Hb = (ushort*)(ws + (size_t)100 * N);   // 3*N*64 bf16 (L1) / 3*N*32 (L2)
  ushort* Bh1 = (ushort*)(ws + (size_t)292 * N);  // 4*128*64
  ushort* Bl1 = Bh1 + 32768;
  ushort* Bh2 = Bl1 + 32768;                      // 4*64*32
  ushort* Bl2 = Bh2 + 8192;
  int* ib     = (int*)(ws + (size_t)293 * N);
  int2* sd    = (int2*)ib;                        // N int2
  int* bstart = ib + 2 * (size_t)N;               // NBUCK+1 (pad to 1024)
  int* hist   = ib + 2 * (size_t)N + 1024;        // NBUCK*256
  size_t roff = 2 * (size_t)N + 1024 + (size_t)NBUCK * 256;
  roff = (roff + 3) & ~(size_t)3;
  unsigned* rec = (unsigned*)(ib + roff);         // E records (1 uint each)
  int* eSrcT  = ib + roff + (size_t)E;            // E

  // --- CSR build: 2-level bucket sort, LDS atomics only ---
  part_hist_kernel<<<256, 256, 0, stream>>>(ei, hist, E, tile, NBUCK);
  part_scan_kernel<<<1, 256, 0, stream>>>(hist, bstart, NBUCK);
  part_scatter_kernel<<<256, 256, 0, stream>>>(ei, et, hist, rec, E, tile, NBUCK);
  bucket_build_kernel<<<NBUCK, 256, 0, stream>>>(rec, bstart, inv4, sd, eSrcT, N);

  // --- weight packing (both layers, one grid) ---
  packw2_kernel<<<(32768 + 8192 + 255) / 256, 256, 0, stream>>>(
      W1, root1, Bh1, Bl1, W2, root2, Bh2, Bl2);

  const int gb = (N + 63) / 64;  // 1 block = 4 waves = 64 rows
  const int pullBlocks = (N * 64 + 255) / 256;

  // --- layer 1: K=128 -> 64 ---
  mfma_gemm_kernel<128, 64><<<gb, 256, 0, stream>>>(x, Bh1, Bl1, b1, Hb, z1, N);
  pull64_kernel<<<pullBlocks, 256, 0, stream>>>(Hb, eSrcT, sd, inv4, z1, N);

  // --- layer 2: K=64 -> 32 ---
  mfma_gemm_kernel<64, 32><<<gb, 256, 0, stream>>>(z1, Bh2, Bl2, b2, Hb, z2, N);
  pull32_kernel<<<pullBlocks, 256, 0, stream>>>(Hb, eSrcT, sd, inv4, z2, N);

  // --- decoder ---
  decoder_kernel<<<(P + 255) / 256, 256, 0, stream>>>(z2, pe, Wd1, bd1, Wd2, bd2, out, P);
}